// Round 11
// baseline (375.629 us; speedup 1.0000x reference)
//
#include <hip/hip_runtime.h>
#include <hip/hip_bf16.h>
#include <cstdint>

#define BB   4
#define TT   2048
#define HH   1024
#define NHH  16
#define DHH  64
#define MM   (BB*TT)      // 8192

typedef __attribute__((ext_vector_type(8))) short short8;   // 8 bf16 = 4 VGPR
typedef __attribute__((ext_vector_type(4))) short short4v;  // 4 bf16 = 2 VGPR
typedef __attribute__((ext_vector_type(4))) float f32x4;

#if __has_builtin(__builtin_amdgcn_exp2f)
#define EXP2F(x) __builtin_amdgcn_exp2f(x)
#else
#define EXP2F(x) exp2f(x)
#endif

// Q pre-scale: (1/sqrt(DH)) * log2(e)  so scores are in log2 domain
#define QSCALE 0.1803368801111204f

__device__ __forceinline__ float bf2f(unsigned short u) {
    return __uint_as_float(((uint32_t)u) << 16);
}
__device__ __forceinline__ unsigned short f2bf(float f) {
    uint32_t u = __float_as_uint(f);
    return (unsigned short)((u + 0x7fffu + ((u >> 16) & 1u)) >> 16);  // RNE
}
__device__ __forceinline__ void gload_lds16(const unsigned short* g, unsigned short* l) {
    __builtin_amdgcn_global_load_lds(
        (const __attribute__((address_space(1))) uint32_t*)g,
        (__attribute__((address_space(3))) uint32_t*)l, 16, 0, 0);
}

// K=16 bf16 MFMA: B-frag layout (B[k=4*quad+j][col=l15]) matches the swapped
// QK^T D layout (S[s=4*quad+r][t=l15]) exactly -> P feeds PV with NO
// cross-lane movement.
__device__ __forceinline__ f32x4 mfma16(short4v a, short4v b, f32x4 c) {
#if __has_builtin(__builtin_amdgcn_mfma_f32_16x16x16bf16_1k)
    return __builtin_amdgcn_mfma_f32_16x16x16bf16_1k(a, b, c, 0, 0, 0);
#else
    f32x4 d;
    asm("v_mfma_f32_16x16x16_bf16 %0, %1, %2, %3"
        : "=v"(d) : "v"(a), "v"(b), "v"(c));
    return d;
#endif
}

// ---------------------------------------------------------------------------
// f32 -> bf16 bulk convert (x)
// ---------------------------------------------------------------------------
__global__ __launch_bounds__(256) void cvt_bf16(
    const float* __restrict__ src, unsigned short* __restrict__ dst, int n4)
{
    int i = blockIdx.x * 256 + threadIdx.x;
    const int stride = gridDim.x * 256;
    for (; i < n4; i += stride) {
        float4 v = ((const float4*)src)[i];
        ushort4 o;
        o.x = f2bf(v.x); o.y = f2bf(v.y); o.z = f2bf(v.z); o.w = f2bf(v.w);
        ((ushort4*)dst)[i] = o;
    }
}

// all three weight matrices in one launch (blockIdx.y selects)
__global__ __launch_bounds__(256) void cvt_w3(
    const float* __restrict__ Wq, const float* __restrict__ Wk,
    const float* __restrict__ Wv, unsigned short* __restrict__ Wb)
{
    const float* src = (blockIdx.y == 0) ? Wq : (blockIdx.y == 1 ? Wk : Wv);
    unsigned short* dst = Wb + (size_t)blockIdx.y * HH * HH;
    const int n4 = HH * HH / 4;
    int i = blockIdx.x * 256 + threadIdx.x;
    const int stride = gridDim.x * 256;
    for (; i < n4; i += stride) {
        float4 v = ((const float4*)src)[i];
        ushort4 o;
        o.x = f2bf(v.x); o.y = f2bf(v.y); o.z = f2bf(v.z); o.w = f2bf(v.w);
        ((ushort4*)dst)[i] = o;
    }
}

// ---------------------------------------------------------------------------
// QKV projection (MFMA 16x16x32, 128x128 tile, BK=32, global_load_lds).
// Q/K: packed [b][h][t][64] via LDS-staged coalesced stores.
// V: stored PRE-FRAGMENTED for flash's PV A-operand:
//   off(d,t) = (t>>5)*2048 + (d>>4)*512 + ((t>>4)&1)*256
//            + (d&15)*16 + ((t>>2)&3)*4 + (t&3)
// so each flash V-fragment wave-load is one 512B fully-contiguous read
// (no LDS, no swizzle, no gather).  8-aligned t-runs remain 16B-contiguous,
// so the epilogue still emits one short8 store per thread.
// Q slab pre-scaled by QSCALE so attention uses native exp2.
// ---------------------------------------------------------------------------
__global__ __launch_bounds__(256) void proj_mfma(
    const unsigned short* __restrict__ xb, const unsigned short* __restrict__ Wb,
    unsigned short* __restrict__ qp, unsigned short* __restrict__ kp,
    unsigned short* __restrict__ vp)
{
    __shared__ unsigned short As[4096];   // 4 kc * 128 m * 8
    __shared__ unsigned short Bs[4096];
    const int m0 = blockIdx.x * 128;
    const int n0 = blockIdx.y * 128;
    const int sel = n0 >> 10;
    const unsigned short* Wbase = Wb + (size_t)sel * HH * HH;
    const int nw0 = n0 & (HH - 1);
    const int tid = threadIdx.x;
    const int wave = tid >> 6, lane = tid & 63;
    const int quad = lane >> 4, l15 = lane & 15;
    const int wm = wave >> 1, wn = wave & 1;

    f32x4 acc[4][4];
    #pragma unroll
    for (int i = 0; i < 4; ++i)
        #pragma unroll
        for (int j = 0; j < 4; ++j) acc[i][j] = (f32x4){0.f, 0.f, 0.f, 0.f};

    for (int k0 = 0; k0 < HH; k0 += 32) {
        __syncthreads();
        #pragma unroll
        for (int q = 0; q < 2; ++q) {
            const int chunk = (wave * 2 + q) * 64 + lane;   // 0..511
            const int kc = chunk >> 7, mrow = chunk & 127;
            gload_lds16(xb    + (size_t)(m0  + mrow) * HH + k0 + kc * 8, As + chunk * 8);
            gload_lds16(Wbase + (size_t)(nw0 + mrow) * HH + k0 + kc * 8, Bs + chunk * 8);
        }
        __syncthreads();
        short8 af[4], bf[4];
        #pragma unroll
        for (int i = 0; i < 4; ++i)
            af[i] = *(const short8*)&As[(quad * 128 + wm * 64 + i * 16 + l15) * 8];
        #pragma unroll
        for (int j = 0; j < 4; ++j)
            bf[j] = *(const short8*)&Bs[(quad * 128 + wn * 64 + j * 16 + l15) * 8];
        #pragma unroll
        for (int i = 0; i < 4; ++i)
            #pragma unroll
            for (int j = 0; j < 4; ++j)
                acc[i][j] = __builtin_amdgcn_mfma_f32_16x16x32_bf16(af[i], bf[j], acc[i][j], 0, 0, 0);
    }

    unsigned short* outp = (sel == 0) ? qp : (sel == 1 ? kp : vp);
    const float cscale = (sel == 0) ? QSCALE : 1.0f;

    // ---- epilogue: LDS-staged per i-band (32 rows x 128 cols bf16) ----
    unsigned short* eb = As;   // 32*128 ushorts = 4096 = sizeof(As)
    const int lr_st = tid >> 3;          // 0..31  (Q/K store-side row)
    const int k8    = tid & 7;           // 0..7
    const int row_g = m0 + ((lr_st & 16) ? 64 : 0) + (lr_st & 15);
    #pragma unroll
    for (int i = 0; i < 4; ++i) {
        __syncthreads();
        #pragma unroll
        for (int j = 0; j < 4; ++j) {
            const int c = wn * 64 + j * 16 + l15;
            #pragma unroll
            for (int r = 0; r < 4; ++r)
                eb[(wm * 16 + quad * 4 + r) * 128 + c] = f2bf(acc[i][j][r] * cscale);
        }
        __syncthreads();
        if (sel < 2) {
            const int row = row_g + i * 16;
            const int bb2 = row >> 11, tt2 = row & (TT - 1);
            {
                const int col = n0 + k8 * 8;
                const int hh2 = (col >> 6) & (NHH - 1);
                *(short8*)(&outp[((size_t)(bb2 * NHH + hh2) * TT + tt2) * DHH + (col & 63)]) =
                    *(const short8*)(&eb[lr_st * 128 + k8 * 8]);
            }
            {
                const int col = n0 + 64 + k8 * 8;
                const int hh2 = (col >> 6) & (NHH - 1);
                *(short8*)(&outp[((size_t)(bb2 * NHH + hh2) * TT + tt2) * DHH + (col & 63)]) =
                    *(const short8*)(&eb[lr_st * 128 + 64 + k8 * 8]);
            }
        } else {
            // V pre-fragmented: 8-t runs (fixed d) are 16B-contiguous
            const int c = tid & 127;          // col in this 128-wide n-window
            const int rn = tid >> 7;          // 0,1 (+2 in loop)
            const int colg = nw0 + c;
            const int hh2 = (colg >> 6) & (NHH - 1);
            const int dd = colg & 63;
            #pragma unroll
            for (int rr = 0; rr < 2; ++rr) {
                const int run = rn + rr * 2;
                const int tb = m0 + ((run >= 2) ? 64 : 0) + i * 16 + (run & 1) * 8;
                const int bb2 = tb >> 11, tt2 = tb & (TT - 1);
                short8 v;
                #pragma unroll
                for (int j = 0; j < 8; ++j)
                    v[j] = (short)eb[(run * 8 + j) * 128 + c];
                const size_t off = (size_t)(bb2 * NHH + hh2) * (TT * DHH)
                    + (tt2 >> 5) * 2048 + (dd >> 4) * 512 + ((tt2 >> 4) & 1) * 256
                    + (dd & 15) * 16 + ((tt2 >> 2) & 3) * 4;
                *(short8*)(&outp[off]) = v;
            }
        }
    }
}

// ---------------------------------------------------------------------------
// Single-pass flash attention + t-mean.
// Grid (h, tblk=32, b) h-major (XCD-local K/V slabs); 4 waves x 16 t-rows
// (2048 blocks = 8/CU -> occupancy cap 100%, attacking the latency gap).
// Per s-step (32 s): K[32][64] (4KB) staged once per block via
// global_load_lds (src-swizzled, ~2-way LDS reads = free); V fragments
// loaded DIRECTLY global->reg from the pre-fragmented layout (512B fully
// contiguous per wave-load) -- eliminates R10's 25M V-read bank conflicts.
// Compute: swapped QK^T (K=32) -> in-register exp2/pack -> K=16 PV
// (B-frag layout identity, zero cross-lane movement).
// No launch_bounds floor (R2/R5: cap->spill).
// ---------------------------------------------------------------------------
__global__ __launch_bounds__(256) void attn_flash(
    const unsigned short* __restrict__ qp, const unsigned short* __restrict__ kp,
    const unsigned short* __restrict__ vt, float* __restrict__ cm)
{
    const int h = blockIdx.x, b = blockIdx.z;
    const int bh = b * NHH + h;
    const int tid = threadIdx.x;
    const int wave = tid >> 6, lane = tid & 63;
    const int quad = lane >> 4, l15 = lane & 15;
    const int t0 = blockIdx.y * 64 + wave * 16;

    __shared__ unsigned short lK[2048];   // [32 s][64 d], chunks src-swizzled

    const unsigned short* q  = qp + (size_t)bh * TT * DHH;
    const unsigned short* kg = kp + (size_t)bh * TT * DHH;
    const unsigned short* vb = vt + (size_t)bh * TT * DHH + l15 * 16 + quad * 4;

    // K staging indices (loop-invariant)
    const int krow = tid >> 3, kc8 = (tid & 7) ^ (krow & 7);

    // Q B-frags (K=32 QK^T): lane holds Q[t=t0+l15][k=quad*8+j (+c*32)]
    short8 aq[2];
    #pragma unroll
    for (int c = 0; c < 2; ++c)
        aq[c] = *(const short8*)&q[(size_t)(t0 + l15) * DHH + quad * 8 + c * 32];

    const f32x4 zk = {0.f, 0.f, 0.f, 0.f};
    f32x4 acc[4];
    #pragma unroll
    for (int dc = 0; dc < 4; ++dc) acc[dc] = zk;
    float den = 0.f;

#define MAKE_P(sreg, preg)                                                   \
    {                                                                        \
        float e0 = EXP2F(sreg[0]), e1 = EXP2F(sreg[1]);                      \
        float e2 = EXP2F(sreg[2]), e3 = EXP2F(sreg[3]);                      \
        den += (e0 + e1) + (e2 + e3);                                        \
        preg[0] = (short)f2bf(e0); preg[1] = (short)f2bf(e1);                \
        preg[2] = (short)f2bf(e2); preg[3] = (short)f2bf(e3);                \
    }

    for (int ss = 0; ss < 64; ++ss) {
        const int s0 = ss * 32;
        __syncthreads();   // previous compute done reading lK
        gload_lds16(kg + (size_t)(s0 + krow) * DHH + kc8 * 8, lK + tid * 8);
        // V fragments: direct, 512B contiguous per wave-load; in flight
        // concurrently with K staging, drained by the barrier's vmcnt(0)
        short4v vf[4][2];
        const unsigned short* vbs = vb + ss * 2048;
        #pragma unroll
        for (int dc = 0; dc < 4; ++dc)
            #pragma unroll
            for (int st = 0; st < 2; ++st)
                vf[dc][st] = *(const short4v*)(vbs + dc * 512 + st * 256);
        __syncthreads();

        // K A-frags: row s=st*16+l15, k-chunks {quad, 4+quad} (de-swizzled)
        short8 kf[2][2];
        #pragma unroll
        for (int st = 0; st < 2; ++st) {
            const int row = st * 16 + l15;
            kf[st][0] = *(const short8*)&lK[row * 64 + ((quad)     ^ (row & 7)) * 8];
            kf[st][1] = *(const short8*)&lK[row * 64 + ((4 + quad) ^ (row & 7)) * 8];
        }

        // QK^T swapped: S[s=16*st+4*quad+r][t=l15]
        f32x4 sf0 = __builtin_amdgcn_mfma_f32_16x16x32_bf16(kf[0][0], aq[0], zk, 0, 0, 0);
        sf0 = __builtin_amdgcn_mfma_f32_16x16x32_bf16(kf[0][1], aq[1], sf0, 0, 0, 0);
        f32x4 sf1 = __builtin_amdgcn_mfma_f32_16x16x32_bf16(kf[1][0], aq[0], zk, 0, 0, 0);
        sf1 = __builtin_amdgcn_mfma_f32_16x16x32_bf16(kf[1][1], aq[1], sf1, 0, 0, 0);

        // exp2 + f32 den + in-register bf16 pack (PV B-operands)
        short4v p0, p1;
        MAKE_P(sf0, p0);
        MAKE_P(sf1, p1);

        // PV (K=16): acc[dc] += V-frag * P-frag
        #pragma unroll
        for (int dc = 0; dc < 4; ++dc) {
            acc[dc] = mfma16(vf[dc][0], p0, acc[dc]);
            acc[dc] = mfma16(vf[dc][1], p1, acc[dc]);
        }
    }
#undef MAKE_P

    // den: quads partition s -> full row-sum per t=l15
    den += __shfl_xor(den, 16);
    den += __shfl_xor(den, 32);
    const float inv = 1.0f / (den * (float)TT);

    // scale by 1/(den(t)*T), sum over t (l15 lanes), atomicAdd per d
    #pragma unroll
    for (int dc = 0; dc < 4; ++dc) {
        #pragma unroll
        for (int r = 0; r < 4; ++r) {
            float v = acc[dc][r] * inv;
            v += __shfl_xor(v, 1); v += __shfl_xor(v, 2);
            v += __shfl_xor(v, 4); v += __shfl_xor(v, 8);
            if (l15 == 0)
                atomicAdd(&cm[b * HH + h * DHH + dc * 16 + quad * 4 + r], v);
        }
    }
}

// ---------------------------------------------------------------------------
// out[b][j] = bo[j] + sum_k cm[b][k] * Wo[j][k]
// ---------------------------------------------------------------------------
__global__ __launch_bounds__(256) void out_proj(
    const float* __restrict__ cm, const float* __restrict__ Wo,
    const float* __restrict__ bo, float* __restrict__ out)
{
    const int b = blockIdx.y;
    const int jb = blockIdx.x;
    const int tid = threadIdx.x;
    const int j = jb * 64 + (tid >> 2);
    const int kg = tid & 3;
    __shared__ float cs[HH];
    for (int k = tid; k < HH; k += 256) cs[k] = cm[b * HH + k];
    __syncthreads();
    float acc = 0.f;
    const float* wrow = &Wo[(size_t)j * HH];
    #pragma unroll 8
    for (int i = 0; i < 64; ++i) {
        const int k = kg * 256 + i * 4;
        float4 w4 = *(const float4*)&wrow[k];
        acc += w4.x * cs[k] + w4.y * cs[k+1] + w4.z * cs[k+2] + w4.w * cs[k+3];
    }
    acc += __shfl_down(acc, 2, 4);
    acc += __shfl_down(acc, 1, 4);
    if (kg == 0) out[b * HH + j] = acc + bo[j];
}

// ---------------------------------------------------------------------------
extern "C" void kernel_launch(void* const* d_in, const int* in_sizes, int n_in,
                              void* d_out, int out_size, void* d_ws, size_t ws_size,
                              hipStream_t stream) {
    const float* x  = (const float*)d_in[0];
    const float* Wq = (const float*)d_in[1];
    const float* Wk = (const float*)d_in[2];
    const float* Wv = (const float*)d_in[3];
    const float* Wo = (const float*)d_in[4];
    const float* bo = (const float*)d_in[5];
    float* out = (float*)d_out;

    char* ws = (char*)d_ws;
    unsigned short* qp = (unsigned short*)ws;  ws += (size_t)MM * HH * 2;  // 16.78 MB
    unsigned short* kp = (unsigned short*)ws;  ws += (size_t)MM * HH * 2;
    unsigned short* vt = (unsigned short*)ws;  ws += (size_t)MM * HH * 2;  // fragged
    unsigned short* xb = (unsigned short*)ws;  ws += (size_t)MM * HH * 2;
    unsigned short* Wb = (unsigned short*)ws;  ws += (size_t)3 * HH * HH * 2;
    float* cm = (float*)ws;

    hipMemsetAsync(cm, 0, (size_t)BB * HH * 4, stream);

    cvt_bf16<<<2048, 256, 0, stream>>>(x, xb, MM * HH / 4);
    cvt_w3  <<<dim3(512, 3), 256, 0, stream>>>(Wq, Wk, Wv, Wb);

    proj_mfma <<<dim3(64, 24),      256, 0, stream>>>(xb, Wb, qp, kp, vt);
    attn_flash<<<dim3(NHH, 32, BB), 256, 0, stream>>>(qp, kp, vt, cm);
    out_proj  <<<dim3(16, BB),      256, 0, stream>>>(cm, Wo, bo, out);
}

// Round 12
// 331.985 us; speedup vs baseline: 1.1315x; 1.1315x over previous
//
#include <hip/hip_runtime.h>
#include <hip/hip_bf16.h>
#include <cstdint>

#define BB   4
#define TT   2048
#define HH   1024
#define NHH  16
#define DHH  64
#define MM   (BB*TT)      // 8192

typedef __attribute__((ext_vector_type(8))) short short8;   // 8 bf16 = 4 VGPR
typedef __attribute__((ext_vector_type(4))) short short4v;  // 4 bf16 = 2 VGPR
typedef __attribute__((ext_vector_type(4))) float f32x4;

#if __has_builtin(__builtin_amdgcn_exp2f)
#define EXP2F(x) __builtin_amdgcn_exp2f(x)
#else
#define EXP2F(x) exp2f(x)
#endif

// Q pre-scale: (1/sqrt(DH)) * log2(e)  so scores are in log2 domain
#define QSCALE 0.1803368801111204f

__device__ __forceinline__ float bf2f(unsigned short u) {
    return __uint_as_float(((uint32_t)u) << 16);
}
__device__ __forceinline__ unsigned short f2bf(float f) {
    uint32_t u = __float_as_uint(f);
    return (unsigned short)((u + 0x7fffu + ((u >> 16) & 1u)) >> 16);  // RNE
}
__device__ __forceinline__ void gload_lds16(const unsigned short* g, unsigned short* l) {
    __builtin_amdgcn_global_load_lds(
        (const __attribute__((address_space(1))) uint32_t*)g,
        (__attribute__((address_space(3))) uint32_t*)l, 16, 0, 0);
}

// K=16 bf16 MFMA: B-frag layout (B[k=4*quad+j][col=l15]) matches the swapped
// QK^T D layout (S[s=4*quad+r][t=l15]) exactly -> P feeds PV with NO
// cross-lane movement.
__device__ __forceinline__ f32x4 mfma16(short4v a, short4v b, f32x4 c) {
#if __has_builtin(__builtin_amdgcn_mfma_f32_16x16x16bf16_1k)
    return __builtin_amdgcn_mfma_f32_16x16x16bf16_1k(a, b, c, 0, 0, 0);
#else
    f32x4 d;
    asm("v_mfma_f32_16x16x16_bf16 %0, %1, %2, %3"
        : "=v"(d) : "v"(a), "v"(b), "v"(c));
    return d;
#endif
}

// ---------------------------------------------------------------------------
// f32 -> bf16 bulk convert (x)
// ---------------------------------------------------------------------------
__global__ __launch_bounds__(256) void cvt_bf16(
    const float* __restrict__ src, unsigned short* __restrict__ dst, int n4)
{
    int i = blockIdx.x * 256 + threadIdx.x;
    const int stride = gridDim.x * 256;
    for (; i < n4; i += stride) {
        float4 v = ((const float4*)src)[i];
        ushort4 o;
        o.x = f2bf(v.x); o.y = f2bf(v.y); o.z = f2bf(v.z); o.w = f2bf(v.w);
        ((ushort4*)dst)[i] = o;
    }
}

// all three weight matrices in one launch (blockIdx.y selects)
__global__ __launch_bounds__(256) void cvt_w3(
    const float* __restrict__ Wq, const float* __restrict__ Wk,
    const float* __restrict__ Wv, unsigned short* __restrict__ Wb)
{
    const float* src = (blockIdx.y == 0) ? Wq : (blockIdx.y == 1 ? Wk : Wv);
    unsigned short* dst = Wb + (size_t)blockIdx.y * HH * HH;
    const int n4 = HH * HH / 4;
    int i = blockIdx.x * 256 + threadIdx.x;
    const int stride = gridDim.x * 256;
    for (; i < n4; i += stride) {
        float4 v = ((const float4*)src)[i];
        ushort4 o;
        o.x = f2bf(v.x); o.y = f2bf(v.y); o.z = f2bf(v.z); o.w = f2bf(v.w);
        ((ushort4*)dst)[i] = o;
    }
}

// ---------------------------------------------------------------------------
// QKV projection (MFMA 16x16x32, 128x128 tile, BK=32, global_load_lds).
// Q/K: packed [b][h][t][64] via LDS-staged coalesced stores.
// V: stored PRE-FRAGMENTED for flash's PV A-operand:
//   off(d,t) = (t>>5)*2048 + (d>>4)*512 + ((t>>4)&1)*256
//            + (d&15)*16 + ((t>>2)&3)*4 + (t&3)
// so each flash V-fragment wave-load is one 512B fully-contiguous read.
// Q slab pre-scaled by QSCALE so attention uses native exp2.
// ---------------------------------------------------------------------------
__global__ __launch_bounds__(256) void proj_mfma(
    const unsigned short* __restrict__ xb, const unsigned short* __restrict__ Wb,
    unsigned short* __restrict__ qp, unsigned short* __restrict__ kp,
    unsigned short* __restrict__ vp)
{
    __shared__ unsigned short As[4096];   // 4 kc * 128 m * 8
    __shared__ unsigned short Bs[4096];
    const int m0 = blockIdx.x * 128;
    const int n0 = blockIdx.y * 128;
    const int sel = n0 >> 10;
    const unsigned short* Wbase = Wb + (size_t)sel * HH * HH;
    const int nw0 = n0 & (HH - 1);
    const int tid = threadIdx.x;
    const int wave = tid >> 6, lane = tid & 63;
    const int quad = lane >> 4, l15 = lane & 15;
    const int wm = wave >> 1, wn = wave & 1;

    f32x4 acc[4][4];
    #pragma unroll
    for (int i = 0; i < 4; ++i)
        #pragma unroll
        for (int j = 0; j < 4; ++j) acc[i][j] = (f32x4){0.f, 0.f, 0.f, 0.f};

    for (int k0 = 0; k0 < HH; k0 += 32) {
        __syncthreads();
        #pragma unroll
        for (int q = 0; q < 2; ++q) {
            const int chunk = (wave * 2 + q) * 64 + lane;   // 0..511
            const int kc = chunk >> 7, mrow = chunk & 127;
            gload_lds16(xb    + (size_t)(m0  + mrow) * HH + k0 + kc * 8, As + chunk * 8);
            gload_lds16(Wbase + (size_t)(nw0 + mrow) * HH + k0 + kc * 8, Bs + chunk * 8);
        }
        __syncthreads();
        short8 af[4], bf[4];
        #pragma unroll
        for (int i = 0; i < 4; ++i)
            af[i] = *(const short8*)&As[(quad * 128 + wm * 64 + i * 16 + l15) * 8];
        #pragma unroll
        for (int j = 0; j < 4; ++j)
            bf[j] = *(const short8*)&Bs[(quad * 128 + wn * 64 + j * 16 + l15) * 8];
        #pragma unroll
        for (int i = 0; i < 4; ++i)
            #pragma unroll
            for (int j = 0; j < 4; ++j)
                acc[i][j] = __builtin_amdgcn_mfma_f32_16x16x32_bf16(af[i], bf[j], acc[i][j], 0, 0, 0);
    }

    unsigned short* outp = (sel == 0) ? qp : (sel == 1 ? kp : vp);
    const float cscale = (sel == 0) ? QSCALE : 1.0f;

    // ---- epilogue: LDS-staged per i-band (32 rows x 128 cols bf16) ----
    unsigned short* eb = As;   // 32*128 ushorts = 4096 = sizeof(As)
    const int lr_st = tid >> 3;          // 0..31  (Q/K store-side row)
    const int k8    = tid & 7;           // 0..7
    const int row_g = m0 + ((lr_st & 16) ? 64 : 0) + (lr_st & 15);
    #pragma unroll
    for (int i = 0; i < 4; ++i) {
        __syncthreads();
        #pragma unroll
        for (int j = 0; j < 4; ++j) {
            const int c = wn * 64 + j * 16 + l15;
            #pragma unroll
            for (int r = 0; r < 4; ++r)
                eb[(wm * 16 + quad * 4 + r) * 128 + c] = f2bf(acc[i][j][r] * cscale);
        }
        __syncthreads();
        if (sel < 2) {
            const int row = row_g + i * 16;
            const int bb2 = row >> 11, tt2 = row & (TT - 1);
            {
                const int col = n0 + k8 * 8;
                const int hh2 = (col >> 6) & (NHH - 1);
                *(short8*)(&outp[((size_t)(bb2 * NHH + hh2) * TT + tt2) * DHH + (col & 63)]) =
                    *(const short8*)(&eb[lr_st * 128 + k8 * 8]);
            }
            {
                const int col = n0 + 64 + k8 * 8;
                const int hh2 = (col >> 6) & (NHH - 1);
                *(short8*)(&outp[((size_t)(bb2 * NHH + hh2) * TT + tt2) * DHH + (col & 63)]) =
                    *(const short8*)(&eb[lr_st * 128 + 64 + k8 * 8]);
            }
        } else {
            // V pre-fragmented: 8-t runs (fixed d) are 16B-contiguous
            const int c = tid & 127;          // col in this 128-wide n-window
            const int rn = tid >> 7;          // 0,1 (+2 in loop)
            const int colg = nw0 + c;
            const int hh2 = (colg >> 6) & (NHH - 1);
            const int dd = colg & 63;
            #pragma unroll
            for (int rr = 0; rr < 2; ++rr) {
                const int run = rn + rr * 2;
                const int tb = m0 + ((run >= 2) ? 64 : 0) + i * 16 + (run & 1) * 8;
                const int bb2 = tb >> 11, tt2 = tb & (TT - 1);
                short8 v;
                #pragma unroll
                for (int j = 0; j < 8; ++j)
                    v[j] = (short)eb[(run * 8 + j) * 128 + c];
                const size_t off = (size_t)(bb2 * NHH + hh2) * (TT * DHH)
                    + (tt2 >> 5) * 2048 + (dd >> 4) * 512 + ((tt2 >> 4) & 1) * 256
                    + (dd & 15) * 16 + ((tt2 >> 2) & 3) * 4;
                *(short8*)(&outp[off]) = v;
            }
        }
    }
}

// ---------------------------------------------------------------------------
// Single-pass flash attention + t-mean.
// R10 geometry (4 waves x 32 t-rows, grid 16h x 16tblk x 4b = 1024 blocks)
// + R11 V path (direct global->reg from pre-fragmented layout, 512B
// contiguous per wave-load, zero LDS-V, zero conflicts).  R11 proved the
// K LDS swizzle conflict-free; R10 proved this compute-per-barrier ratio
// reaches 30% MfmaUtil even WITH 25M conflict cycles (~41 us) -- removing
// them is the remaining delta.  Per iter/wave: 8 K=32 QK^T + 16 K=16 PV.
// V fragment loads issue before the staging barrier (in flight across it).
// No launch_bounds floor (R2/R5: cap->spill).
// ---------------------------------------------------------------------------
__global__ __launch_bounds__(256) void attn_flash(
    const unsigned short* __restrict__ qp, const unsigned short* __restrict__ kp,
    const unsigned short* __restrict__ vt, float* __restrict__ cm)
{
    const int h = blockIdx.x, b = blockIdx.z;
    const int bh = b * NHH + h;
    const int tid = threadIdx.x;
    const int wave = tid >> 6, lane = tid & 63;
    const int quad = lane >> 4, l15 = lane & 15;
    const int t0 = blockIdx.y * 128 + wave * 32;

    __shared__ unsigned short lK[2048];   // [32 s][64 d], chunks src-swizzled

    const unsigned short* q  = qp + (size_t)bh * TT * DHH;
    const unsigned short* kg = kp + (size_t)bh * TT * DHH;
    const unsigned short* vb = vt + (size_t)bh * TT * DHH + l15 * 16 + quad * 4;

    // K staging indices (loop-invariant)
    const int krow = tid >> 3, kc8 = (tid & 7) ^ (krow & 7);

    // Q B-frags (K=32 QK^T): lane holds Q[t=t0+g*16+l15][k=quad*8+j (+c*32)]
    short8 aq[2][2];
    #pragma unroll
    for (int g = 0; g < 2; ++g)
        #pragma unroll
        for (int c = 0; c < 2; ++c)
            aq[g][c] = *(const short8*)&q[(size_t)(t0 + g * 16 + l15) * DHH + quad * 8 + c * 32];

    const f32x4 zk = {0.f, 0.f, 0.f, 0.f};
    f32x4 acc[2][4];
    #pragma unroll
    for (int g = 0; g < 2; ++g)
        #pragma unroll
        for (int dc = 0; dc < 4; ++dc) acc[g][dc] = zk;
    float den0 = 0.f, den1 = 0.f;

#define MAKE_P(sreg, den, preg)                                              \
    {                                                                        \
        float e0 = EXP2F(sreg[0]), e1 = EXP2F(sreg[1]);                      \
        float e2 = EXP2F(sreg[2]), e3 = EXP2F(sreg[3]);                      \
        den += (e0 + e1) + (e2 + e3);                                        \
        preg[0] = (short)f2bf(e0); preg[1] = (short)f2bf(e1);                \
        preg[2] = (short)f2bf(e2); preg[3] = (short)f2bf(e3);                \
    }

    for (int ss = 0; ss < 64; ++ss) {
        const int s0 = ss * 32;
        __syncthreads();   // previous compute done reading lK
        gload_lds16(kg + (size_t)(s0 + krow) * DHH + kc8 * 8, lK + tid * 8);
        // V fragments: direct, 512B contiguous per wave-load; in flight
        // concurrently with K staging, drained by the barrier's vmcnt(0)
        short4v vf[4][2];
        const unsigned short* vbs = vb + ss * 2048;
        #pragma unroll
        for (int dc = 0; dc < 4; ++dc)
            #pragma unroll
            for (int st = 0; st < 2; ++st)
                vf[dc][st] = *(const short4v*)(vbs + dc * 512 + st * 256);
        __syncthreads();

        // K A-frags: row s=st*16+l15, k-chunks {quad, 4+quad} (de-swizzled)
        short8 kf[2][2];
        #pragma unroll
        for (int st = 0; st < 2; ++st) {
            const int row = st * 16 + l15;
            kf[st][0] = *(const short8*)&lK[row * 64 + ((quad)     ^ (row & 7)) * 8];
            kf[st][1] = *(const short8*)&lK[row * 64 + ((4 + quad) ^ (row & 7)) * 8];
        }

        // QK^T swapped: S[s=16*st+4*quad+r][t=l15] per row-group g
        f32x4 s00 = __builtin_amdgcn_mfma_f32_16x16x32_bf16(kf[0][0], aq[0][0], zk, 0, 0, 0);
        s00 = __builtin_amdgcn_mfma_f32_16x16x32_bf16(kf[0][1], aq[0][1], s00, 0, 0, 0);
        f32x4 s01 = __builtin_amdgcn_mfma_f32_16x16x32_bf16(kf[1][0], aq[0][0], zk, 0, 0, 0);
        s01 = __builtin_amdgcn_mfma_f32_16x16x32_bf16(kf[1][1], aq[0][1], s01, 0, 0, 0);
        f32x4 s10 = __builtin_amdgcn_mfma_f32_16x16x32_bf16(kf[0][0], aq[1][0], zk, 0, 0, 0);
        s10 = __builtin_amdgcn_mfma_f32_16x16x32_bf16(kf[0][1], aq[1][1], s10, 0, 0, 0);
        f32x4 s11 = __builtin_amdgcn_mfma_f32_16x16x32_bf16(kf[1][0], aq[1][0], zk, 0, 0, 0);
        s11 = __builtin_amdgcn_mfma_f32_16x16x32_bf16(kf[1][1], aq[1][1], s11, 0, 0, 0);

        // exp2 + f32 den + in-register bf16 pack (PV B-operands)
        short4v p00, p01, p10, p11;
        MAKE_P(s00, den0, p00);
        MAKE_P(s01, den0, p01);
        MAKE_P(s10, den1, p10);
        MAKE_P(s11, den1, p11);

        // PV (K=16): acc[g][dc] += V-frag * P-frag
        #pragma unroll
        for (int dc = 0; dc < 4; ++dc) {
            acc[0][dc] = mfma16(vf[dc][0], p00, acc[0][dc]);
            acc[0][dc] = mfma16(vf[dc][1], p01, acc[0][dc]);
            acc[1][dc] = mfma16(vf[dc][0], p10, acc[1][dc]);
            acc[1][dc] = mfma16(vf[dc][1], p11, acc[1][dc]);
        }
    }
#undef MAKE_P

    // den: quads partition s -> full row-sum per t=l15
    den0 += __shfl_xor(den0, 16); den0 += __shfl_xor(den0, 32);
    den1 += __shfl_xor(den1, 16); den1 += __shfl_xor(den1, 32);
    const float inv0 = 1.0f / (den0 * (float)TT);
    const float inv1 = 1.0f / (den1 * (float)TT);

    // scale by 1/(den(t)*T), sum over t (l15 lanes), atomicAdd per d
    #pragma unroll
    for (int dc = 0; dc < 4; ++dc) {
        #pragma unroll
        for (int r = 0; r < 4; ++r) {
            float v = acc[0][dc][r] * inv0 + acc[1][dc][r] * inv1;
            v += __shfl_xor(v, 1); v += __shfl_xor(v, 2);
            v += __shfl_xor(v, 4); v += __shfl_xor(v, 8);
            if (l15 == 0)
                atomicAdd(&cm[b * HH + h * DHH + dc * 16 + quad * 4 + r], v);
        }
    }
}

// ---------------------------------------------------------------------------
// out[b][j] = bo[j] + sum_k cm[b][k] * Wo[j][k]
// ---------------------------------------------------------------------------
__global__ __launch_bounds__(256) void out_proj(
    const float* __restrict__ cm, const float* __restrict__ Wo,
    const float* __restrict__ bo, float* __restrict__ out)
{
    const int b = blockIdx.y;
    const int jb = blockIdx.x;
    const int tid = threadIdx.x;
    const int j = jb * 64 + (tid >> 2);
    const int kg = tid & 3;
    __shared__ float cs[HH];
    for (int k = tid; k < HH; k += 256) cs[k] = cm[b * HH + k];
    __syncthreads();
    float acc = 0.f;
    const float* wrow = &Wo[(size_t)j * HH];
    #pragma unroll 8
    for (int i = 0; i < 64; ++i) {
        const int k = kg * 256 + i * 4;
        float4 w4 = *(const float4*)&wrow[k];
        acc += w4.x * cs[k] + w4.y * cs[k+1] + w4.z * cs[k+2] + w4.w * cs[k+3];
    }
    acc += __shfl_down(acc, 2, 4);
    acc += __shfl_down(acc, 1, 4);
    if (kg == 0) out[b * HH + j] = acc + bo[j];
}

// ---------------------------------------------------------------------------
extern "C" void kernel_launch(void* const* d_in, const int* in_sizes, int n_in,
                              void* d_out, int out_size, void* d_ws, size_t ws_size,
                              hipStream_t stream) {
    const float* x  = (const float*)d_in[0];
    const float* Wq = (const float*)d_in[1];
    const float* Wk = (const float*)d_in[2];
    const float* Wv = (const float*)d_in[3];
    const float* Wo = (const float*)d_in[4];
    const float* bo = (const float*)d_in[5];
    float* out = (float*)d_out;

    char* ws = (char*)d_ws;
    unsigned short* qp = (unsigned short*)ws;  ws += (size_t)MM * HH * 2;  // 16.78 MB
    unsigned short* kp = (unsigned short*)ws;  ws += (size_t)MM * HH * 2;
    unsigned short* vt = (unsigned short*)ws;  ws += (size_t)MM * HH * 2;  // fragged
    unsigned short* xb = (unsigned short*)ws;  ws += (size_t)MM * HH * 2;
    unsigned short* Wb = (unsigned short*)ws;  ws += (size_t)3 * HH * HH * 2;
    float* cm = (float*)ws;

    hipMemsetAsync(cm, 0, (size_t)BB * HH * 4, stream);

    cvt_bf16<<<2048, 256, 0, stream>>>(x, xb, MM * HH / 4);
    cvt_w3  <<<dim3(512, 3), 256, 0, stream>>>(Wq, Wk, Wv, Wb);

    proj_mfma <<<dim3(64, 24),      256, 0, stream>>>(xb, Wb, qp, kp, vt);
    attn_flash<<<dim3(NHH, 16, BB), 256, 0, stream>>>(qp, kp, vt, cm);
    out_proj  <<<dim3(16, BB),      256, 0, stream>>>(cm, Wo, bo, out);
}

// Round 13
// 328.237 us; speedup vs baseline: 1.1444x; 1.0114x over previous
//
#include <hip/hip_runtime.h>
#include <hip/hip_bf16.h>
#include <cstdint>

#define BB   4
#define TT   2048
#define HH   1024
#define NHH  16
#define DHH  64
#define MM   (BB*TT)      // 8192

typedef __attribute__((ext_vector_type(8))) short short8;   // 8 bf16 = 4 VGPR
typedef __attribute__((ext_vector_type(4))) short short4v;  // 4 bf16 = 2 VGPR
typedef __attribute__((ext_vector_type(4))) float f32x4;

#if __has_builtin(__builtin_amdgcn_exp2f)
#define EXP2F(x) __builtin_amdgcn_exp2f(x)
#else
#define EXP2F(x) exp2f(x)
#endif

// Q pre-scale: (1/sqrt(DH)) * log2(e)  so scores are in log2 domain
#define QSCALE 0.1803368801111204f

__device__ __forceinline__ float bf2f(unsigned short u) {
    return __uint_as_float(((uint32_t)u) << 16);
}
__device__ __forceinline__ unsigned short f2bf(float f) {
    uint32_t u = __float_as_uint(f);
    return (unsigned short)((u + 0x7fffu + ((u >> 16) & 1u)) >> 16);  // RNE
}
__device__ __forceinline__ void gload_lds16(const unsigned short* g, unsigned short* l) {
    __builtin_amdgcn_global_load_lds(
        (const __attribute__((address_space(1))) uint32_t*)g,
        (__attribute__((address_space(3))) uint32_t*)l, 16, 0, 0);
}

// K=16 bf16 MFMA: B-frag layout (B[k=4*quad+j][col=l15]) matches the swapped
// QK^T D layout (S[s=4*quad+r][t=l15]) exactly -> P feeds PV with NO
// cross-lane movement.
__device__ __forceinline__ f32x4 mfma16(short4v a, short4v b, f32x4 c) {
#if __has_builtin(__builtin_amdgcn_mfma_f32_16x16x16bf16_1k)
    return __builtin_amdgcn_mfma_f32_16x16x16bf16_1k(a, b, c, 0, 0, 0);
#else
    f32x4 d;
    asm("v_mfma_f32_16x16x16_bf16 %0, %1, %2, %3"
        : "=v"(d) : "v"(a), "v"(b), "v"(c));
    return d;
#endif
}

// ---------------------------------------------------------------------------
// f32 -> bf16 bulk convert (x)
// ---------------------------------------------------------------------------
__global__ __launch_bounds__(256) void cvt_bf16(
    const float* __restrict__ src, unsigned short* __restrict__ dst, int n4)
{
    int i = blockIdx.x * 256 + threadIdx.x;
    const int stride = gridDim.x * 256;
    for (; i < n4; i += stride) {
        float4 v = ((const float4*)src)[i];
        ushort4 o;
        o.x = f2bf(v.x); o.y = f2bf(v.y); o.z = f2bf(v.z); o.w = f2bf(v.w);
        ((ushort4*)dst)[i] = o;
    }
}

// all three weight matrices in one launch (blockIdx.y selects)
__global__ __launch_bounds__(256) void cvt_w3(
    const float* __restrict__ Wq, const float* __restrict__ Wk,
    const float* __restrict__ Wv, unsigned short* __restrict__ Wb)
{
    const float* src = (blockIdx.y == 0) ? Wq : (blockIdx.y == 1 ? Wk : Wv);
    unsigned short* dst = Wb + (size_t)blockIdx.y * HH * HH;
    const int n4 = HH * HH / 4;
    int i = blockIdx.x * 256 + threadIdx.x;
    const int stride = gridDim.x * 256;
    for (; i < n4; i += stride) {
        float4 v = ((const float4*)src)[i];
        ushort4 o;
        o.x = f2bf(v.x); o.y = f2bf(v.y); o.z = f2bf(v.z); o.w = f2bf(v.w);
        ((ushort4*)dst)[i] = o;
    }
}

// ---------------------------------------------------------------------------
// QKV projection (MFMA 16x16x32, 128x128 tile, BK=32, global_load_lds).
// Q/K: packed [b][h][t][64] via LDS-staged coalesced stores.
// V: stored PRE-FRAGMENTED for flash's PV A-operand:
//   off(d,t) = (t>>5)*2048 + (d>>4)*512 + ((t>>4)&1)*256
//            + (d&15)*16 + ((t>>2)&3)*4 + (t&3)
// so each flash V-fragment wave-load is one 512B fully-contiguous read.
// Q slab pre-scaled by QSCALE so attention uses native exp2.
// ---------------------------------------------------------------------------
__global__ __launch_bounds__(256) void proj_mfma(
    const unsigned short* __restrict__ xb, const unsigned short* __restrict__ Wb,
    unsigned short* __restrict__ qp, unsigned short* __restrict__ kp,
    unsigned short* __restrict__ vp)
{
    __shared__ unsigned short As[4096];   // 4 kc * 128 m * 8
    __shared__ unsigned short Bs[4096];
    const int m0 = blockIdx.x * 128;
    const int n0 = blockIdx.y * 128;
    const int sel = n0 >> 10;
    const unsigned short* Wbase = Wb + (size_t)sel * HH * HH;
    const int nw0 = n0 & (HH - 1);
    const int tid = threadIdx.x;
    const int wave = tid >> 6, lane = tid & 63;
    const int quad = lane >> 4, l15 = lane & 15;
    const int wm = wave >> 1, wn = wave & 1;

    f32x4 acc[4][4];
    #pragma unroll
    for (int i = 0; i < 4; ++i)
        #pragma unroll
        for (int j = 0; j < 4; ++j) acc[i][j] = (f32x4){0.f, 0.f, 0.f, 0.f};

    for (int k0 = 0; k0 < HH; k0 += 32) {
        __syncthreads();
        #pragma unroll
        for (int q = 0; q < 2; ++q) {
            const int chunk = (wave * 2 + q) * 64 + lane;   // 0..511
            const int kc = chunk >> 7, mrow = chunk & 127;
            gload_lds16(xb    + (size_t)(m0  + mrow) * HH + k0 + kc * 8, As + chunk * 8);
            gload_lds16(Wbase + (size_t)(nw0 + mrow) * HH + k0 + kc * 8, Bs + chunk * 8);
        }
        __syncthreads();
        short8 af[4], bf[4];
        #pragma unroll
        for (int i = 0; i < 4; ++i)
            af[i] = *(const short8*)&As[(quad * 128 + wm * 64 + i * 16 + l15) * 8];
        #pragma unroll
        for (int j = 0; j < 4; ++j)
            bf[j] = *(const short8*)&Bs[(quad * 128 + wn * 64 + j * 16 + l15) * 8];
        #pragma unroll
        for (int i = 0; i < 4; ++i)
            #pragma unroll
            for (int j = 0; j < 4; ++j)
                acc[i][j] = __builtin_amdgcn_mfma_f32_16x16x32_bf16(af[i], bf[j], acc[i][j], 0, 0, 0);
    }

    unsigned short* outp = (sel == 0) ? qp : (sel == 1 ? kp : vp);
    const float cscale = (sel == 0) ? QSCALE : 1.0f;

    // ---- epilogue: LDS-staged per i-band (32 rows x 128 cols bf16) ----
    unsigned short* eb = As;   // 32*128 ushorts = 4096 = sizeof(As)
    const int lr_st = tid >> 3;          // 0..31  (Q/K store-side row)
    const int k8    = tid & 7;           // 0..7
    const int row_g = m0 + ((lr_st & 16) ? 64 : 0) + (lr_st & 15);
    #pragma unroll
    for (int i = 0; i < 4; ++i) {
        __syncthreads();
        #pragma unroll
        for (int j = 0; j < 4; ++j) {
            const int c = wn * 64 + j * 16 + l15;
            #pragma unroll
            for (int r = 0; r < 4; ++r)
                eb[(wm * 16 + quad * 4 + r) * 128 + c] = f2bf(acc[i][j][r] * cscale);
        }
        __syncthreads();
        if (sel < 2) {
            const int row = row_g + i * 16;
            const int bb2 = row >> 11, tt2 = row & (TT - 1);
            {
                const int col = n0 + k8 * 8;
                const int hh2 = (col >> 6) & (NHH - 1);
                *(short8*)(&outp[((size_t)(bb2 * NHH + hh2) * TT + tt2) * DHH + (col & 63)]) =
                    *(const short8*)(&eb[lr_st * 128 + k8 * 8]);
            }
            {
                const int col = n0 + 64 + k8 * 8;
                const int hh2 = (col >> 6) & (NHH - 1);
                *(short8*)(&outp[((size_t)(bb2 * NHH + hh2) * TT + tt2) * DHH + (col & 63)]) =
                    *(const short8*)(&eb[lr_st * 128 + 64 + k8 * 8]);
            }
        } else {
            // V pre-fragmented: 8-t runs (fixed d) are 16B-contiguous
            const int c = tid & 127;          // col in this 128-wide n-window
            const int rn = tid >> 7;          // 0,1 (+2 in loop)
            const int colg = nw0 + c;
            const int hh2 = (colg >> 6) & (NHH - 1);
            const int dd = colg & 63;
            #pragma unroll
            for (int rr = 0; rr < 2; ++rr) {
                const int run = rn + rr * 2;
                const int tb = m0 + ((run >= 2) ? 64 : 0) + i * 16 + (run & 1) * 8;
                const int bb2 = tb >> 11, tt2 = tb & (TT - 1);
                short8 v;
                #pragma unroll
                for (int j = 0; j < 8; ++j)
                    v[j] = (short)eb[(run * 8 + j) * 128 + c];
                const size_t off = (size_t)(bb2 * NHH + hh2) * (TT * DHH)
                    + (tt2 >> 5) * 2048 + (dd >> 4) * 512 + ((tt2 >> 4) & 1) * 256
                    + (dd & 15) * 16 + ((tt2 >> 2) & 3) * 4;
                *(short8*)(&outp[off]) = v;
            }
        }
    }
}

// ---------------------------------------------------------------------------
// Single-pass flash attention + t-mean.
// R12 + single-barrier double-buffered K staging:
//   per iter: barrier -> stage K(ss+1)->lK[cur^1] -> load V(ss)->reg
//             -> compute(ss) from lK[cur]
// Barriers halve (128->64); K staging is in flight across the WHOLE compute
// phase; V loads have no intervening barrier before PV, so the compiler
// emits a counted vmcnt (not a drain) -- QK^T+exp2 covers the L2 latency.
// This attacks the measured 25% idle gap (R12: Mfma 28 + VALU 47 = 75%).
// LDS dbuf indexing is memory-based (no rule-#20 register hazard).
// Per iter/wave: 8 K=32 QK^T + 16 K=16 PV.  No launch_bounds floor.
// ---------------------------------------------------------------------------
__global__ __launch_bounds__(256) void attn_flash(
    const unsigned short* __restrict__ qp, const unsigned short* __restrict__ kp,
    const unsigned short* __restrict__ vt, float* __restrict__ cm)
{
    const int h = blockIdx.x, b = blockIdx.z;
    const int bh = b * NHH + h;
    const int tid = threadIdx.x;
    const int wave = tid >> 6, lane = tid & 63;
    const int quad = lane >> 4, l15 = lane & 15;
    const int t0 = blockIdx.y * 128 + wave * 32;

    __shared__ unsigned short lK[2][2048];   // double-buffered [32 s][64 d]

    const unsigned short* q  = qp + (size_t)bh * TT * DHH;
    const unsigned short* kg = kp + (size_t)bh * TT * DHH;
    const unsigned short* vb = vt + (size_t)bh * TT * DHH + l15 * 16 + quad * 4;

    // K staging indices (loop-invariant)
    const int krow = tid >> 3, kc8 = (tid & 7) ^ (krow & 7);

    // Q B-frags (K=32 QK^T): lane holds Q[t=t0+g*16+l15][k=quad*8+j (+c*32)]
    short8 aq[2][2];
    #pragma unroll
    for (int g = 0; g < 2; ++g)
        #pragma unroll
        for (int c = 0; c < 2; ++c)
            aq[g][c] = *(const short8*)&q[(size_t)(t0 + g * 16 + l15) * DHH + quad * 8 + c * 32];

    const f32x4 zk = {0.f, 0.f, 0.f, 0.f};
    f32x4 acc[2][4];
    #pragma unroll
    for (int g = 0; g < 2; ++g)
        #pragma unroll
        for (int dc = 0; dc < 4; ++dc) acc[g][dc] = zk;
    float den0 = 0.f, den1 = 0.f;

    // prologue: stage K(0) into lK[0] (drained by first top-barrier)
    gload_lds16(kg + (size_t)krow * DHH + kc8 * 8, &lK[0][tid * 8]);

#define MAKE_P(sreg, den, preg)                                              \
    {                                                                        \
        float e0 = EXP2F(sreg[0]), e1 = EXP2F(sreg[1]);                      \
        float e2 = EXP2F(sreg[2]), e3 = EXP2F(sreg[3]);                      \
        den += (e0 + e1) + (e2 + e3);                                        \
        preg[0] = (short)f2bf(e0); preg[1] = (short)f2bf(e1);                \
        preg[2] = (short)f2bf(e2); preg[3] = (short)f2bf(e3);                \
    }

    for (int ss = 0; ss < 64; ++ss) {
        const int cur = ss & 1;
        __syncthreads();   // lK[cur] staged; prior reads of lK[cur^1] done
        if (ss < 63)
            gload_lds16(kg + (size_t)((ss + 1) * 32 + krow) * DHH + kc8 * 8,
                        &lK[cur ^ 1][tid * 8]);
        // V fragments: issued here, consumed at PV after QK^T+exp2 --
        // counted vmcnt (no barrier between issue and use)
        short4v vf[4][2];
        const unsigned short* vbs = vb + ss * 2048;
        #pragma unroll
        for (int dc = 0; dc < 4; ++dc)
            #pragma unroll
            for (int st = 0; st < 2; ++st)
                vf[dc][st] = *(const short4v*)(vbs + dc * 512 + st * 256);

        // K A-frags: row s=st*16+l15, k-chunks {quad, 4+quad} (de-swizzled)
        short8 kf[2][2];
        #pragma unroll
        for (int st = 0; st < 2; ++st) {
            const int row = st * 16 + l15;
            kf[st][0] = *(const short8*)&lK[cur][row * 64 + ((quad)     ^ (row & 7)) * 8];
            kf[st][1] = *(const short8*)&lK[cur][row * 64 + ((4 + quad) ^ (row & 7)) * 8];
        }

        // QK^T swapped: S[s=16*st+4*quad+r][t=l15] per row-group g
        f32x4 s00 = __builtin_amdgcn_mfma_f32_16x16x32_bf16(kf[0][0], aq[0][0], zk, 0, 0, 0);
        s00 = __builtin_amdgcn_mfma_f32_16x16x32_bf16(kf[0][1], aq[0][1], s00, 0, 0, 0);
        f32x4 s01 = __builtin_amdgcn_mfma_f32_16x16x32_bf16(kf[1][0], aq[0][0], zk, 0, 0, 0);
        s01 = __builtin_amdgcn_mfma_f32_16x16x32_bf16(kf[1][1], aq[0][1], s01, 0, 0, 0);
        f32x4 s10 = __builtin_amdgcn_mfma_f32_16x16x32_bf16(kf[0][0], aq[1][0], zk, 0, 0, 0);
        s10 = __builtin_amdgcn_mfma_f32_16x16x32_bf16(kf[0][1], aq[1][1], s10, 0, 0, 0);
        f32x4 s11 = __builtin_amdgcn_mfma_f32_16x16x32_bf16(kf[1][0], aq[1][0], zk, 0, 0, 0);
        s11 = __builtin_amdgcn_mfma_f32_16x16x32_bf16(kf[1][1], aq[1][1], s11, 0, 0, 0);

        // exp2 + f32 den + in-register bf16 pack (PV B-operands)
        short4v p00, p01, p10, p11;
        MAKE_P(s00, den0, p00);
        MAKE_P(s01, den0, p01);
        MAKE_P(s10, den1, p10);
        MAKE_P(s11, den1, p11);

        // PV (K=16): acc[g][dc] += V-frag * P-frag
        #pragma unroll
        for (int dc = 0; dc < 4; ++dc) {
            acc[0][dc] = mfma16(vf[dc][0], p00, acc[0][dc]);
            acc[0][dc] = mfma16(vf[dc][1], p01, acc[0][dc]);
            acc[1][dc] = mfma16(vf[dc][0], p10, acc[1][dc]);
            acc[1][dc] = mfma16(vf[dc][1], p11, acc[1][dc]);
        }
    }
#undef MAKE_P

    // den: quads partition s -> full row-sum per t=l15
    den0 += __shfl_xor(den0, 16); den0 += __shfl_xor(den0, 32);
    den1 += __shfl_xor(den1, 16); den1 += __shfl_xor(den1, 32);
    const float inv0 = 1.0f / (den0 * (float)TT);
    const float inv1 = 1.0f / (den1 * (float)TT);

    // scale by 1/(den(t)*T), sum over t (l15 lanes), atomicAdd per d
    #pragma unroll
    for (int dc = 0; dc < 4; ++dc) {
        #pragma unroll
        for (int r = 0; r < 4; ++r) {
            float v = acc[0][dc][r] * inv0 + acc[1][dc][r] * inv1;
            v += __shfl_xor(v, 1); v += __shfl_xor(v, 2);
            v += __shfl_xor(v, 4); v += __shfl_xor(v, 8);
            if (l15 == 0)
                atomicAdd(&cm[b * HH + h * DHH + dc * 16 + quad * 4 + r], v);
        }
    }
}

// ---------------------------------------------------------------------------
// out[b][j] = bo[j] + sum_k cm[b][k] * Wo[j][k]
// ---------------------------------------------------------------------------
__global__ __launch_bounds__(256) void out_proj(
    const float* __restrict__ cm, const float* __restrict__ Wo,
    const float* __restrict__ bo, float* __restrict__ out)
{
    const int b = blockIdx.y;
    const int jb = blockIdx.x;
    const int tid = threadIdx.x;
    const int j = jb * 64 + (tid >> 2);
    const int kg = tid & 3;
    __shared__ float cs[HH];
    for (int k = tid; k < HH; k += 256) cs[k] = cm[b * HH + k];
    __syncthreads();
    float acc = 0.f;
    const float* wrow = &Wo[(size_t)j * HH];
    #pragma unroll 8
    for (int i = 0; i < 64; ++i) {
        const int k = kg * 256 + i * 4;
        float4 w4 = *(const float4*)&wrow[k];
        acc += w4.x * cs[k] + w4.y * cs[k+1] + w4.z * cs[k+2] + w4.w * cs[k+3];
    }
    acc += __shfl_down(acc, 2, 4);
    acc += __shfl_down(acc, 1, 4);
    if (kg == 0) out[b * HH + j] = acc + bo[j];
}

// ---------------------------------------------------------------------------
extern "C" void kernel_launch(void* const* d_in, const int* in_sizes, int n_in,
                              void* d_out, int out_size, void* d_ws, size_t ws_size,
                              hipStream_t stream) {
    const float* x  = (const float*)d_in[0];
    const float* Wq = (const float*)d_in[1];
    const float* Wk = (const float*)d_in[2];
    const float* Wv = (const float*)d_in[3];
    const float* Wo = (const float*)d_in[4];
    const float* bo = (const float*)d_in[5];
    float* out = (float*)d_out;

    char* ws = (char*)d_ws;
    unsigned short* qp = (unsigned short*)ws;  ws += (size_t)MM * HH * 2;  // 16.78 MB
    unsigned short* kp = (unsigned short*)ws;  ws += (size_t)MM * HH * 2;
    unsigned short* vt = (unsigned short*)ws;  ws += (size_t)MM * HH * 2;  // fragged
    unsigned short* xb = (unsigned short*)ws;  ws += (size_t)MM * HH * 2;
    unsigned short* Wb = (unsigned short*)ws;  ws += (size_t)3 * HH * HH * 2;
    float* cm = (float*)ws;

    hipMemsetAsync(cm, 0, (size_t)BB * HH * 4, stream);

    cvt_bf16<<<2048, 256, 0, stream>>>(x, xb, MM * HH / 4);
    cvt_w3  <<<dim3(512, 3), 256, 0, stream>>>(Wq, Wk, Wv, Wb);

    proj_mfma <<<dim3(64, 24),      256, 0, stream>>>(xb, Wb, qp, kp, vt);
    attn_flash<<<dim3(NHH, 16, BB), 256, 0, stream>>>(qp, kp, vt, cm);
    out_proj  <<<dim3(16, BB),      256, 0, stream>>>(cm, Wo, bo, out);
}

// Round 14
// 322.781 us; speedup vs baseline: 1.1637x; 1.0169x over previous
//
#include <hip/hip_runtime.h>
#include <hip/hip_bf16.h>
#include <cstdint>

#define BB   4
#define TT   2048
#define HH   1024
#define NHH  16
#define DHH  64
#define MM   (BB*TT)      // 8192
#define N3   (3*HH)       // 3072

typedef __attribute__((ext_vector_type(8))) short short8;   // 8 bf16 = 4 VGPR
typedef __attribute__((ext_vector_type(4))) float f32x4;

#if __has_builtin(__builtin_amdgcn_exp2f)
#define EXP2F(x) __builtin_amdgcn_exp2f(x)
#else
#define EXP2F(x) exp2f(x)
#endif

// Q pre-scale: (1/sqrt(DH)) * log2(e)  so scores are in log2 domain
#define QSCALE 0.1803368801111204f

__device__ __forceinline__ float bf2f(unsigned short u) {
    return __uint_as_float(((uint32_t)u) << 16);
}
__device__ __forceinline__ unsigned short f2bf(float f) {
    uint32_t u = __float_as_uint(f);
    return (unsigned short)((u + 0x7fffu + ((u >> 16) & 1u)) >> 16);  // RNE
}
__device__ __forceinline__ void gload_lds16(const unsigned short* g, unsigned short* l) {
    __builtin_amdgcn_global_load_lds(
        (const __attribute__((address_space(1))) uint32_t*)g,
        (__attribute__((address_space(3))) uint32_t*)l, 16, 0, 0);
}

// ---------------------------------------------------------------------------
// f32 -> bf16 bulk convert (x)
// ---------------------------------------------------------------------------
__global__ __launch_bounds__(256) void cvt_bf16(
    const float* __restrict__ src, unsigned short* __restrict__ dst, int n4)
{
    int i = blockIdx.x * 256 + threadIdx.x;
    const int stride = gridDim.x * 256;
    for (; i < n4; i += stride) {
        float4 v = ((const float4*)src)[i];
        ushort4 o;
        o.x = f2bf(v.x); o.y = f2bf(v.y); o.z = f2bf(v.z); o.w = f2bf(v.w);
        ((ushort4*)dst)[i] = o;
    }
}

// all three weight matrices in one launch (blockIdx.y selects)
__global__ __launch_bounds__(256) void cvt_w3(
    const float* __restrict__ Wq, const float* __restrict__ Wk,
    const float* __restrict__ Wv, unsigned short* __restrict__ Wb)
{
    const float* src = (blockIdx.y == 0) ? Wq : (blockIdx.y == 1 ? Wk : Wv);
    unsigned short* dst = Wb + (size_t)blockIdx.y * HH * HH;
    const int n4 = HH * HH / 4;
    int i = blockIdx.x * 256 + threadIdx.x;
    const int stride = gridDim.x * 256;
    for (; i < n4; i += stride) {
        float4 v = ((const float4*)src)[i];
        ushort4 o;
        o.x = f2bf(v.x); o.y = f2bf(v.y); o.z = f2bf(v.z); o.w = f2bf(v.w);
        ((ushort4*)dst)[i] = o;
    }
}

// ---------------------------------------------------------------------------
// QKV projection (MFMA 16x16x32, 128x128 tile, BK=32, global_load_lds).
// Epilogue writes packed per-head tensors qp/kp/vp[b][h][t][64] (bf16);
// Q slab pre-scaled by QSCALE so attention uses native exp2.
// ---------------------------------------------------------------------------
__global__ __launch_bounds__(256) void proj_mfma(
    const unsigned short* __restrict__ xb, const unsigned short* __restrict__ Wb,
    unsigned short* __restrict__ qp, unsigned short* __restrict__ kp,
    unsigned short* __restrict__ vp)
{
    __shared__ unsigned short As[4096];   // 4 kc * 128 m * 8
    __shared__ unsigned short Bs[4096];
    const int m0 = blockIdx.x * 128;
    const int n0 = blockIdx.y * 128;
    const int sel = n0 >> 10;
    const unsigned short* Wbase = Wb + (size_t)sel * HH * HH;
    const int nw0 = n0 & (HH - 1);
    const int tid = threadIdx.x;
    const int wave = tid >> 6, lane = tid & 63;
    const int quad = lane >> 4, l15 = lane & 15;
    const int wm = wave >> 1, wn = wave & 1;

    f32x4 acc[4][4];
    #pragma unroll
    for (int i = 0; i < 4; ++i)
        #pragma unroll
        for (int j = 0; j < 4; ++j) acc[i][j] = (f32x4){0.f, 0.f, 0.f, 0.f};

    for (int k0 = 0; k0 < HH; k0 += 32) {
        __syncthreads();
        #pragma unroll
        for (int q = 0; q < 2; ++q) {
            const int chunk = (wave * 2 + q) * 64 + lane;   // 0..511
            const int kc = chunk >> 7, mrow = chunk & 127;
            gload_lds16(xb    + (size_t)(m0  + mrow) * HH + k0 + kc * 8, As + chunk * 8);
            gload_lds16(Wbase + (size_t)(nw0 + mrow) * HH + k0 + kc * 8, Bs + chunk * 8);
        }
        __syncthreads();
        short8 af[4], bf[4];
        #pragma unroll
        for (int i = 0; i < 4; ++i)
            af[i] = *(const short8*)&As[(quad * 128 + wm * 64 + i * 16 + l15) * 8];
        #pragma unroll
        for (int j = 0; j < 4; ++j)
            bf[j] = *(const short8*)&Bs[(quad * 128 + wn * 64 + j * 16 + l15) * 8];
        #pragma unroll
        for (int i = 0; i < 4; ++i)
            #pragma unroll
            for (int j = 0; j < 4; ++j)
                acc[i][j] = __builtin_amdgcn_mfma_f32_16x16x32_bf16(af[i], bf[j], acc[i][j], 0, 0, 0);
    }
    unsigned short* outp = (sel == 0) ? qp : (sel == 1 ? kp : vp);
    const float cscale = (sel == 0) ? QSCALE : 1.0f;
    #pragma unroll
    for (int i = 0; i < 4; ++i)
        #pragma unroll
        for (int j = 0; j < 4; ++j) {
            const int col = n0 + wn * 64 + j * 16 + l15;
            const int hh2 = (col >> 6) & (NHH - 1);
            const int dd  = col & (DHH - 1);
            #pragma unroll
            for (int r = 0; r < 4; ++r) {
                const int row = m0 + wm * 64 + i * 16 + quad * 4 + r;
                const int bb2 = row >> 11, tt2 = row & (TT - 1);
                outp[((size_t)(bb2 * NHH + hh2) * TT + tt2) * DHH + dd] =
                    f2bf(acc[i][j][r] * cscale);
            }
        }
}

// ---------------------------------------------------------------------------
// Fused attention over packed layout (R1 structure: 128 t-rows per block,
// grid 16 h x 16 tblk x 4 b, h-major for XCD-local K slabs):
//   phase 1: l_t = sum_s exp2(S[t,s]);  linv[t] = 1/(l_t*T)
//   phase 2: a[b,h,s] += sum_t exp2(S[t,s]) * linv[t]   (atomics)
// 1-step skew ILP: row-group i's MFMA pair issues while row-group i-1's
// exp2/accumulate executes.  Session-proven floor for this algorithm at
// HIP level: ~118 us (2 waves/SIMD; occupancy unsteerable — R2/R5
// cap->spill, R3/R4 restructure->inflation; flash alternative R7-R13
// never beat this barrier-free streaming structure).
// ---------------------------------------------------------------------------
__global__ __launch_bounds__(256) void attn_fused(
    const unsigned short* __restrict__ qp, const unsigned short* __restrict__ kp,
    float* __restrict__ a)
{
    const int h = blockIdx.x, b = blockIdx.z;
    const int t0 = blockIdx.y * 128;   // 16 t-blocks
    const int bh = b * NHH + h;
    const int tid = threadIdx.x;
    const int wave = tid >> 6, lane = tid & 63;
    const int quad = lane >> 4, l15 = lane & 15;
    __shared__ float red[4][128];
    __shared__ float linv[128];

    const unsigned short* q = qp + (size_t)bh * TT * DHH;
    const unsigned short* kbase =
        kp + (size_t)bh * TT * DHH + (size_t)(wave * 512 + l15) * DHH + quad * 8;

    // A-frags: 8 row-groups of 16 t; k split 0..31 / 32..63
    short8 aq[8][2];
    #pragma unroll
    for (int i = 0; i < 8; ++i)
        #pragma unroll
        for (int c = 0; c < 2; ++c)
            aq[i][c] = *(const short8*)&q[(size_t)(t0 + i * 16 + l15) * DHH + quad * 8 + c * 32];

    const f32x4 zk = {0.f, 0.f, 0.f, 0.f};   // loop-invariant MFMA C operand

    // ---- phase 1: row sums ----
    float rs[8][4];
    #pragma unroll
    for (int i = 0; i < 8; ++i)
        #pragma unroll
        for (int r = 0; r < 4; ++r) rs[i][r] = 0.f;

    {
        const unsigned short* kw = kbase;
        short8 c0a = *(const short8*)(kw);
        short8 c0b = *(const short8*)(kw + 32);
        kw += 16 * DHH;
        short8 c1a = *(const short8*)(kw);
        short8 c1b = *(const short8*)(kw + 32);
        kw += 16 * DHH;
        for (int ss = 0; ss < 32; ++ss) {
            const short8 ba = c0a, bb = c0b;
            c0a = c1a; c0b = c1b;
            if (ss < 30) {
                c1a = *(const short8*)(kw);
                c1b = *(const short8*)(kw + 32);
            }
            kw += 16 * DHH;
            // skewed pipeline: MFMA(i) overlaps exp2/acc(i-1)
            f32x4 pc = __builtin_amdgcn_mfma_f32_16x16x32_bf16(aq[0][0], ba, zk, 0, 0, 0);
            pc = __builtin_amdgcn_mfma_f32_16x16x32_bf16(aq[0][1], bb, pc, 0, 0, 0);
            #pragma unroll
            for (int i = 1; i < 8; ++i) {
                f32x4 c = __builtin_amdgcn_mfma_f32_16x16x32_bf16(aq[i][0], ba, zk, 0, 0, 0);
                c = __builtin_amdgcn_mfma_f32_16x16x32_bf16(aq[i][1], bb, c, 0, 0, 0);
                #pragma unroll
                for (int r = 0; r < 4; ++r) rs[i - 1][r] += EXP2F(pc[r]);
                pc = c;
            }
            #pragma unroll
            for (int r = 0; r < 4; ++r) rs[7][r] += EXP2F(pc[r]);
        }
    }
    #pragma unroll
    for (int off = 1; off < 16; off <<= 1)
        #pragma unroll
        for (int i = 0; i < 8; ++i)
            #pragma unroll
            for (int r = 0; r < 4; ++r) rs[i][r] += __shfl_xor(rs[i][r], off);
    if (l15 == 0)
        #pragma unroll
        for (int i = 0; i < 8; ++i)
            #pragma unroll
            for (int r = 0; r < 4; ++r) red[wave][i * 16 + quad * 4 + r] = rs[i][r];
    __syncthreads();
    if (tid < 128) {
        const float l = red[0][tid] + red[1][tid] + red[2][tid] + red[3][tid];
        linv[tid] = 1.0f / (l * (float)TT);
    }
    __syncthreads();

    // ---- phase 2: column sums ----
    float lrv[8][4];
    #pragma unroll
    for (int i = 0; i < 8; ++i)
        #pragma unroll
        for (int r = 0; r < 4; ++r) lrv[i][r] = linv[i * 16 + quad * 4 + r];

    float* ap = a + (size_t)bh * TT + wave * 512 + l15;

    {
        const unsigned short* kw = kbase;
        short8 c0a = *(const short8*)(kw);
        short8 c0b = *(const short8*)(kw + 32);
        kw += 16 * DHH;
        short8 c1a = *(const short8*)(kw);
        short8 c1b = *(const short8*)(kw + 32);
        kw += 16 * DHH;
        for (int ss = 0; ss < 32; ++ss) {
            const short8 ba = c0a, bb = c0b;
            c0a = c1a; c0b = c1b;
            if (ss < 30) {
                c1a = *(const short8*)(kw);
                c1b = *(const short8*)(kw + 32);
            }
            kw += 16 * DHH;
            float cs = 0.f;
            // skewed pipeline: MFMA(i) overlaps exp2/fma(i-1)
            f32x4 pc = __builtin_amdgcn_mfma_f32_16x16x32_bf16(aq[0][0], ba, zk, 0, 0, 0);
            pc = __builtin_amdgcn_mfma_f32_16x16x32_bf16(aq[0][1], bb, pc, 0, 0, 0);
            #pragma unroll
            for (int i = 1; i < 8; ++i) {
                f32x4 c = __builtin_amdgcn_mfma_f32_16x16x32_bf16(aq[i][0], ba, zk, 0, 0, 0);
                c = __builtin_amdgcn_mfma_f32_16x16x32_bf16(aq[i][1], bb, c, 0, 0, 0);
                #pragma unroll
                for (int r = 0; r < 4; ++r) cs += EXP2F(pc[r]) * lrv[i - 1][r];
                pc = c;
            }
            #pragma unroll
            for (int r = 0; r < 4; ++r) cs += EXP2F(pc[r]) * lrv[7][r];
            cs += __shfl_xor(cs, 16);
            cs += __shfl_xor(cs, 32);
            if (lane < 16)
                atomicAdd(&ap[ss * 16], cs);
        }
    }
}

// ---------------------------------------------------------------------------
// cm[b, h*64+d] += sum_{s in sblock} a[b,h,s] * V[b,h,s,d]   (packed V)
// ---------------------------------------------------------------------------
__global__ __launch_bounds__(256) void ctx_mean(
    const unsigned short* __restrict__ vp, const float* __restrict__ a,
    float* __restrict__ cm)
{
    const int h = blockIdx.x, b = blockIdx.y, sb = blockIdx.z;
    const int tid = threadIdx.x;
    const int d = tid & 63, sg = tid >> 6;
    const int bh = b * NHH + h;
    __shared__ float red[4][64];
    float part = 0.f;
    for (int s = sb * 256 + sg; s < sb * 256 + 256; s += 4) {
        const float av = a[(size_t)bh * TT + s];
        part += av * bf2f(vp[((size_t)bh * TT + s) * DHH + d]);
    }
    red[sg][d] = part;
    __syncthreads();
    if (tid < 64)
        atomicAdd(&cm[b * HH + h * DHH + tid],
                  red[0][tid] + red[1][tid] + red[2][tid] + red[3][tid]);
}

// ---------------------------------------------------------------------------
// out[b][j] = bo[j] + sum_k cm[b][k] * Wo[j][k]
// ---------------------------------------------------------------------------
__global__ __launch_bounds__(256) void out_proj(
    const float* __restrict__ cm, const float* __restrict__ Wo,
    const float* __restrict__ bo, float* __restrict__ out)
{
    const int b = blockIdx.y;
    const int jb = blockIdx.x;
    const int tid = threadIdx.x;
    const int j = jb * 64 + (tid >> 2);
    const int kg = tid & 3;
    __shared__ float cs[HH];
    for (int k = tid; k < HH; k += 256) cs[k] = cm[b * HH + k];
    __syncthreads();
    float acc = 0.f;
    const float* wrow = &Wo[(size_t)j * HH];
    #pragma unroll 8
    for (int i = 0; i < 64; ++i) {
        const int k = kg * 256 + i * 4;
        float4 w4 = *(const float4*)&wrow[k];
        acc += w4.x * cs[k] + w4.y * cs[k+1] + w4.z * cs[k+2] + w4.w * cs[k+3];
    }
    acc += __shfl_down(acc, 2, 4);
    acc += __shfl_down(acc, 1, 4);
    if (kg == 0) out[b * HH + j] = acc + bo[j];
}

// ---------------------------------------------------------------------------
extern "C" void kernel_launch(void* const* d_in, const int* in_sizes, int n_in,
                              void* d_out, int out_size, void* d_ws, size_t ws_size,
                              hipStream_t stream) {
    const float* x  = (const float*)d_in[0];
    const float* Wq = (const float*)d_in[1];
    const float* Wk = (const float*)d_in[2];
    const float* Wv = (const float*)d_in[3];
    const float* Wo = (const float*)d_in[4];
    const float* bo = (const float*)d_in[5];
    float* out = (float*)d_out;

    char* ws = (char*)d_ws;
    unsigned short* qp = (unsigned short*)ws;  ws += (size_t)MM * HH * 2;  // 16.78 MB
    unsigned short* kp = (unsigned short*)ws;  ws += (size_t)MM * HH * 2;
    unsigned short* vp = (unsigned short*)ws;  ws += (size_t)MM * HH * 2;
    unsigned short* xb = (unsigned short*)ws;  ws += (size_t)MM * HH * 2;
    unsigned short* Wb = (unsigned short*)ws;  ws += (size_t)3 * HH * HH * 2;
    float* a  = (float*)ws;                    ws += (size_t)BB * NHH * TT * 4;
    float* cm = (float*)ws;

    hipMemsetAsync(a, 0, (size_t)(BB * NHH * TT + BB * HH) * 4, stream);  // a + cm

    cvt_bf16<<<2048, 256, 0, stream>>>(x, xb, MM * HH / 4);
    cvt_w3  <<<dim3(512, 3), 256, 0, stream>>>(Wq, Wk, Wv, Wb);

    proj_mfma <<<dim3(64, 24),      256, 0, stream>>>(xb, Wb, qp, kp, vp);
    attn_fused<<<dim3(NHH, 16, BB), 256, 0, stream>>>(qp, kp, a);
    ctx_mean  <<<dim3(NHH, BB, 8),  256, 0, stream>>>(vp, a, cm);
    out_proj  <<<dim3(16, BB),      256, 0, stream>>>(cm, Wo, bo, out);
}